// Round 1
// baseline (313.209 us; speedup 1.0000x reference)
//
#include <hip/hip_runtime.h>
#include <stdint.h>

typedef unsigned short ushort_t;
typedef __attribute__((ext_vector_type(8))) __bf16 bf16x8;
typedef __attribute__((ext_vector_type(4))) float f32x4;

// ---------- helpers ----------

__device__ __forceinline__ unsigned short f2bf(float f) {
    unsigned int u = __float_as_uint(f);
    unsigned int r = (u + 0x7FFFu + ((u >> 16) & 1u)) >> 16;  // RNE
    return (unsigned short)r;
}

// Cayley sign for e_a * e_b in Cl(4,1), SIG = [1,1,1,1,-1]
__device__ __forceinline__ float cayley_sign(int a, int b) {
    int s = 0;
    int aa = a >> 1;
    while (aa) { s += __popc(aa & b); aa >>= 1; }
    float sign = (s & 1) ? -1.0f : 1.0f;
    if (a & b & 16) sign = -sign;   // only SIG[4] = -1
    return sign;
}

// async global->LDS, 16 bytes per lane. LDS dest is wave-uniform base + lane*16.
__device__ __forceinline__ void async16(const ushort_t* g, const ushort_t* l) {
    const __attribute__((address_space(1))) unsigned int* gp =
        (const __attribute__((address_space(1))) unsigned int*)(uintptr_t)g;
    __attribute__((address_space(3))) unsigned int* lp =
        (__attribute__((address_space(3))) unsigned int*)(unsigned int)(uintptr_t)l;
    __builtin_amdgcn_global_load_lds(gp, lp, 16, 0, 0);
}

// ---------- prep kernels ----------
// Swizzled operand layout: chunk(blk, k_blk) = 4096 bf16 elements laid out as
// [kq(4)][row(128)][j(8)]  (element off = kq*1024 + row*8 + j).
// Chunk order: blk-major, k_blk fastest (streaming along K in the GEMM loop).

// A: x (4096 x 128 x 32 f32) viewed as M=4096 x K=4096 row-major. Cast->bf16 + swizzle.
__global__ void prepA(const float* __restrict__ x, ushort_t* __restrict__ A_sw) {
    const int k_blk = blockIdx.x;      // 0..127
    const int m_blk = blockIdx.y;      // 0..31
    const int t = threadIdx.x;         // 0..255
    const int row = t & 127;
    const int kq  = t >> 7;            // 0..1 ... wait: 256 threads -> kq 0..1? no: t>>7 = 0..1
    // 256 threads cover 2048 elements (8 each); chunk has 4096 -> each thread does 2 groups.
    // Simpler: thread handles elements t*8 and (t+256)*8? Keep: do both halves.
    const size_t chunk = ((size_t)m_blk * 128 + k_blk) * 4096;
#pragma unroll
    for (int half = 0; half < 2; ++half) {
        const int e = t + half * 256;          // 0..511, element group index
        const int kqq = e >> 7;                // 0..3
        const int r   = e & 127;               // row
        const float* src = x + (size_t)(m_blk * 128 + r) * 4096 + (size_t)k_blk * 32 + kqq * 8;
        float4 f0 = ((const float4*)src)[0];
        float4 f1 = ((const float4*)src)[1];
        unsigned int p0 = (unsigned int)f2bf(f0.x) | ((unsigned int)f2bf(f0.y) << 16);
        unsigned int p1 = (unsigned int)f2bf(f0.z) | ((unsigned int)f2bf(f0.w) << 16);
        unsigned int p2 = (unsigned int)f2bf(f1.x) | ((unsigned int)f2bf(f1.y) << 16);
        unsigned int p3 = (unsigned int)f2bf(f1.z) | ((unsigned int)f2bf(f1.w) << 16);
        uint4 packed = {p0, p1, p2, p3};
        ((uint4*)(A_sw + chunk))[e] = packed;
    }
}

// B: Bt[n][kd] = W[o, f, i^kc] * sgn(i, i^kc),  n = o*32+kc, kd = f*32+i.
// Same swizzled chunk layout, N plays the role of "row" (col).
__global__ void prepB(const float* __restrict__ w, ushort_t* __restrict__ B_sw) {
    const int k_blk = blockIdx.x;      // 0..127  (== f)
    const int n_blk = blockIdx.y;      // 0..31
    const int t = threadIdx.x;
    const size_t chunk = ((size_t)n_blk * 128 + k_blk) * 4096;
#pragma unroll
    for (int half = 0; half < 2; ++half) {
        const int e = t + half * 256;          // 0..511
        const int kq  = e >> 7;                // 0..3
        const int col = e & 127;
        const int n  = n_blk * 128 + col;
        const int o  = n >> 5;
        const int kc = n & 31;
        const int f  = k_blk;
        const float* wrow = w + (size_t)o * 4096 + (size_t)f * 32;  // 32 floats
        unsigned int p[4];
#pragma unroll
        for (int pair = 0; pair < 4; ++pair) {
            int jj0 = pair * 2, jj1 = pair * 2 + 1;
            int i0 = kq * 8 + jj0, i1 = kq * 8 + jj1;
            int j0 = i0 ^ kc, j1 = i1 ^ kc;
            float v0 = wrow[j0] * cayley_sign(i0, j0);
            float v1 = wrow[j1] * cayley_sign(i1, j1);
            p[pair] = (unsigned int)f2bf(v0) | ((unsigned int)f2bf(v1) << 16);
        }
        uint4 packed = {p[0], p[1], p[2], p[3]};
        ((uint4*)(B_sw + chunk))[e] = packed;
    }
}

// ---------- GEMM + fused multivector normalization ----------
// C[b, n] = sum_kd A[b,kd] * Bt[n,kd];  out[b,n] = C[b,n] * rsqrt(sum_{kc in n's group} C^2 + 1e-6)
__global__ __launch_bounds__(256) void gemm_norm(const ushort_t* __restrict__ A_sw,
                                                 const ushort_t* __restrict__ B_sw,
                                                 float* __restrict__ out) {
    __shared__ ushort_t As[4096];  // 8 KiB: [kq][row][j]
    __shared__ ushort_t Bs[4096];  // 8 KiB: [kq][col][j]

    const int n_blk = blockIdx.x;  // 0..31
    const int m_blk = blockIdx.y;  // 0..31
    const int t = threadIdx.x;
    const int wave = t >> 6;
    const int lane = t & 63;
    const int quad = lane >> 4;
    const int l16  = lane & 15;
    const int wr = wave >> 1;      // 0..1  wave row
    const int wc = wave & 1;       // 0..1  wave col

    f32x4 acc[4][4];
    const f32x4 zero = {0.f, 0.f, 0.f, 0.f};
#pragma unroll
    for (int a = 0; a < 4; ++a)
#pragma unroll
        for (int b = 0; b < 4; ++b) acc[a][b] = zero;

    const ushort_t* aPanel = A_sw + (size_t)m_blk * 128 * 4096;
    const ushort_t* bPanel = B_sw + (size_t)n_blk * 128 * 4096;

    for (int kb = 0; kb < 128; ++kb) {
        const ushort_t* gA = aPanel + (size_t)kb * 4096;
        const ushort_t* gB = bPanel + (size_t)kb * 4096;
        // stage 8 KiB A + 8 KiB B; fully linear: global byte t*16 -> LDS byte t*16
        async16(gA + t * 8,        As + wave * 512);
        async16(gA + 2048 + t * 8, As + 2048 + wave * 512);
        async16(gB + t * 8,        Bs + wave * 512);
        async16(gB + 2048 + t * 8, Bs + 2048 + wave * 512);
        __syncthreads();

        bf16x8 aF[4], bF[4];
#pragma unroll
        for (int tm = 0; tm < 4; ++tm)
            aF[tm] = *(const bf16x8*)&As[quad * 1024 + (wr * 64 + tm * 16 + l16) * 8];
#pragma unroll
        for (int tn = 0; tn < 4; ++tn)
            bF[tn] = *(const bf16x8*)&Bs[quad * 1024 + (wc * 64 + tn * 16 + l16) * 8];

#pragma unroll
        for (int tm = 0; tm < 4; ++tm)
#pragma unroll
            for (int tn = 0; tn < 4; ++tn)
                acc[tm][tn] = __builtin_amdgcn_mfma_f32_16x16x32_bf16(aF[tm], bF[tn], acc[tm][tn], 0, 0, 0);

        __syncthreads();
    }

    // Epilogue: fused normalization over each 32-wide multivector (o-group).
    // C/D layout (16x16x32): col = lane&15, row = quad*4 + reg.
    const int row0 = m_blk * 128 + wr * 64;
    const int col0 = n_blk * 128 + wc * 64;
#pragma unroll
    for (int tm = 0; tm < 4; ++tm) {
#pragma unroll
        for (int r = 0; r < 4; ++r) {
            const int row = row0 + tm * 16 + quad * 4 + r;
            float* orow = out + (size_t)row * 4096;
#pragma unroll
            for (int g = 0; g < 2; ++g) {
                float v0 = acc[tm][2 * g][r];
                float v1 = acc[tm][2 * g + 1][r];
                float p = v0 * v0 + v1 * v1;
                p += __shfl_xor(p, 1);
                p += __shfl_xor(p, 2);
                p += __shfl_xor(p, 4);
                p += __shfl_xor(p, 8);
                const float inv = rsqrtf(p + 1e-6f);
                orow[col0 + (2 * g) * 16 + l16]     = v0 * inv;
                orow[col0 + (2 * g + 1) * 16 + l16] = v1 * inv;
            }
        }
    }
}

// ---------- launch ----------

extern "C" void kernel_launch(void* const* d_in, const int* in_sizes, int n_in,
                              void* d_out, int out_size, void* d_ws, size_t ws_size,
                              hipStream_t stream) {
    const float* x = (const float*)d_in[0];     // 4096 x 128 x 32
    const float* w = (const float*)d_in[1];     // 128 x 128 x 32
    float* out = (float*)d_out;                 // 4096 x 128 x 32

    ushort_t* A_sw = (ushort_t*)d_ws;                       // 32 MiB
    ushort_t* B_sw = A_sw + (size_t)4096 * 4096;            // 32 MiB

    prepA<<<dim3(128, 32), 256, 0, stream>>>(x, A_sw);
    prepB<<<dim3(128, 32), 256, 0, stream>>>(w, B_sw);
    gemm_norm<<<dim3(32, 32), 256, 0, stream>>>(A_sw, B_sw, out);
}

// Round 2
// 286.710 us; speedup vs baseline: 1.0924x; 1.0924x over previous
//
#include <hip/hip_runtime.h>
#include <stdint.h>

typedef unsigned short ushort_t;
typedef __attribute__((ext_vector_type(8))) __bf16 bf16x8;
typedef __attribute__((ext_vector_type(4))) float f32x4;

// ---------- helpers ----------

__device__ __forceinline__ unsigned int f2bf(float f) {
    unsigned int u = __float_as_uint(f);
    return (u + 0x7FFFu + ((u >> 16) & 1u)) >> 16;  // RNE
}

// Cayley sign for e_a * e_b in Cl(4,1), SIG = [1,1,1,1,-1]
__device__ __forceinline__ float cayley_sign(int a, int b) {
    int s = 0;
    int aa = a >> 1;
    while (aa) { s += __popc(aa & b); aa >>= 1; }
    float sign = (s & 1) ? -1.0f : 1.0f;
    if (a & b & 16) sign = -sign;   // only SIG[4] = -1
    return sign;
}

// async global->LDS, 16 bytes per lane. LDS dest is wave-uniform base + lane*16.
__device__ __forceinline__ void async16(const ushort_t* g, const ushort_t* l) {
    const __attribute__((address_space(1))) unsigned int* gp =
        (const __attribute__((address_space(1))) unsigned int*)(uintptr_t)g;
    __attribute__((address_space(3))) unsigned int* lp =
        (__attribute__((address_space(3))) unsigned int*)(unsigned int)(uintptr_t)l;
    __builtin_amdgcn_global_load_lds(gp, lp, 16, 0, 0);
}

// ---------- merged prep kernel ----------
// Swizzled operand chunk(blk, k_blk) = 4096 bf16: [kq(4)][row(128)][j(8)].
// blockIdx.z == 0: A (x cast->bf16), z == 1: B (Cayley-folded weight).
// Thread t owns one row/col: reads 128 B contiguous, writes 4 coalesced uint4
// stores (wave writes 1 KiB contiguous per store instruction).
__global__ __launch_bounds__(128) void prepAB(const float* __restrict__ x,
                                              const float* __restrict__ w,
                                              ushort_t* __restrict__ A_sw,
                                              ushort_t* __restrict__ B_sw) {
    const int k_blk = blockIdx.x;   // 0..127
    const int p_blk = blockIdx.y;   // 0..31
    const int t = threadIdx.x;      // 0..127

    if (blockIdx.z == 0) {
        // ---- A: x viewed as 4096 x 4096 row-major f32 -> bf16 swizzled ----
        const float* src = x + (size_t)(p_blk * 128 + t) * 4096 + (size_t)k_blk * 32;
        uint4* dst = (uint4*)(A_sw + ((size_t)p_blk * 128 + k_blk) * 4096);
        float4 f[8];
#pragma unroll
        for (int q = 0; q < 8; ++q) f[q] = ((const float4*)src)[q];
#pragma unroll
        for (int q = 0; q < 4; ++q) {
            float4 a = f[2 * q], b = f[2 * q + 1];
            uint4 pk;
            pk.x = f2bf(a.x) | (f2bf(a.y) << 16);
            pk.y = f2bf(a.z) | (f2bf(a.w) << 16);
            pk.z = f2bf(b.x) | (f2bf(b.y) << 16);
            pk.w = f2bf(b.z) | (f2bf(b.w) << 16);
            dst[q * 128 + t] = pk;   // coalesced: lane-consecutive 16 B
        }
    } else {
        // ---- B: Bt[n][f*32+i] = W[o, f, i^kc] * sgn(i, i^kc), n = o*32+kc ----
        const int n = p_blk * 128 + t;
        const int o = n >> 5;
        const int kc = n & 31;
        const float* wrow = w + (size_t)o * 4096 + (size_t)k_blk * 32;
        uint4* dst = (uint4*)(B_sw + ((size_t)p_blk * 128 + k_blk) * 4096);
#pragma unroll
        for (int q = 0; q < 4; ++q) {
            unsigned int pk[4];
#pragma unroll
            for (int pr = 0; pr < 4; ++pr) {
                const int i0 = q * 8 + pr * 2, i1 = i0 + 1;
                const int j0 = i0 ^ kc, j1 = i1 ^ kc;
                // 32 lanes sharing o gather a permutation of the same 128 B line
                float v0 = wrow[j0] * cayley_sign(i0, j0);
                float v1 = wrow[j1] * cayley_sign(i1, j1);
                pk[pr] = f2bf(v0) | (f2bf(v1) << 16);
            }
            uint4 u = {pk[0], pk[1], pk[2], pk[3]};
            dst[q * 128 + t] = u;
        }
    }
}

// ---------- GEMM + fused multivector normalization ----------
// Single-barrier double-buffered K-loop: barrier -> prefetch(next) -> compute(cur).
// Prefetch has the full compute phase to land before next barrier's vmcnt drain.
__global__ __launch_bounds__(256) void gemm_norm(const ushort_t* __restrict__ A_sw,
                                                 const ushort_t* __restrict__ B_sw,
                                                 float* __restrict__ out) {
    __shared__ ushort_t As[2][4096];  // 2 x 8 KiB
    __shared__ ushort_t Bs[2][4096];  // 2 x 8 KiB

    const int n_blk = blockIdx.x;  // 0..31
    const int m_blk = blockIdx.y;  // 0..31
    const int t = threadIdx.x;
    const int wave = t >> 6;
    const int lane = t & 63;
    const int quad = lane >> 4;
    const int l16  = lane & 15;
    const int wr = wave >> 1;      // wave row (0..1)
    const int wc = wave & 1;       // wave col (0..1)

    f32x4 acc[4][4];
    const f32x4 zero = {0.f, 0.f, 0.f, 0.f};
#pragma unroll
    for (int a = 0; a < 4; ++a)
#pragma unroll
        for (int b = 0; b < 4; ++b) acc[a][b] = zero;

    const ushort_t* aPanel = A_sw + (size_t)m_blk * 128 * 4096;
    const ushort_t* bPanel = B_sw + (size_t)n_blk * 128 * 4096;

    // prologue: stage k-chunk 0 into buffer 0
    async16(aPanel + t * 8,        As[0] + wave * 512);
    async16(aPanel + 2048 + t * 8, As[0] + 2048 + wave * 512);
    async16(bPanel + t * 8,        Bs[0] + wave * 512);
    async16(bPanel + 2048 + t * 8, Bs[0] + 2048 + wave * 512);

    for (int kb = 0; kb < 128; ++kb) {
        const int cur = kb & 1;
        __syncthreads();   // drains vmcnt -> buf[cur] staged; lgkm drain makes buf[cur^1] safe to overwrite

        if (kb + 1 < 128) {
            const ushort_t* gA = aPanel + (size_t)(kb + 1) * 4096;
            const ushort_t* gB = bPanel + (size_t)(kb + 1) * 4096;
            const int nxt = cur ^ 1;
            async16(gA + t * 8,        As[nxt] + wave * 512);
            async16(gA + 2048 + t * 8, As[nxt] + 2048 + wave * 512);
            async16(gB + t * 8,        Bs[nxt] + wave * 512);
            async16(gB + 2048 + t * 8, Bs[nxt] + 2048 + wave * 512);
        }

        bf16x8 aF[4], bF[4];
#pragma unroll
        for (int tm = 0; tm < 4; ++tm)
            aF[tm] = *(const bf16x8*)&As[cur][quad * 1024 + (wr * 64 + tm * 16 + l16) * 8];
#pragma unroll
        for (int tn = 0; tn < 4; ++tn)
            bF[tn] = *(const bf16x8*)&Bs[cur][quad * 1024 + (wc * 64 + tn * 16 + l16) * 8];

#pragma unroll
        for (int tm = 0; tm < 4; ++tm)
#pragma unroll
            for (int tn = 0; tn < 4; ++tn)
                acc[tm][tn] = __builtin_amdgcn_mfma_f32_16x16x32_bf16(aF[tm], bF[tn], acc[tm][tn], 0, 0, 0);
    }

    // Epilogue: fused normalization over each 32-wide multivector (o-group).
    // C/D layout (16x16x32): col = lane&15, row = quad*4 + reg.
    const int row0 = m_blk * 128 + wr * 64;
    const int col0 = n_blk * 128 + wc * 64;
#pragma unroll
    for (int tm = 0; tm < 4; ++tm) {
#pragma unroll
        for (int r = 0; r < 4; ++r) {
            const int row = row0 + tm * 16 + quad * 4 + r;
            float* orow = out + (size_t)row * 4096;
#pragma unroll
            for (int g = 0; g < 2; ++g) {
                float v0 = acc[tm][2 * g][r];
                float v1 = acc[tm][2 * g + 1][r];
                float p = v0 * v0 + v1 * v1;
                p += __shfl_xor(p, 1);
                p += __shfl_xor(p, 2);
                p += __shfl_xor(p, 4);
                p += __shfl_xor(p, 8);
                const float inv = rsqrtf(p + 1e-6f);
                orow[col0 + (2 * g) * 16 + l16]     = v0 * inv;
                orow[col0 + (2 * g + 1) * 16 + l16] = v1 * inv;
            }
        }
    }
}

// ---------- launch ----------

extern "C" void kernel_launch(void* const* d_in, const int* in_sizes, int n_in,
                              void* d_out, int out_size, void* d_ws, size_t ws_size,
                              hipStream_t stream) {
    const float* x = (const float*)d_in[0];     // 4096 x 128 x 32 f32
    const float* w = (const float*)d_in[1];     // 128 x 128 x 32 f32
    float* out = (float*)d_out;                 // 4096 x 128 x 32 f32

    ushort_t* A_sw = (ushort_t*)d_ws;                       // 32 MiB
    ushort_t* B_sw = A_sw + (size_t)4096 * 4096;            // 32 MiB

    prepAB<<<dim3(128, 32, 2), 128, 0, stream>>>(x, w, A_sw, B_sw);
    gemm_norm<<<dim3(32, 32), 256, 0, stream>>>(A_sw, B_sw, out);
}

// Round 3
// 279.499 us; speedup vs baseline: 1.1206x; 1.0258x over previous
//
#include <hip/hip_runtime.h>
#include <stdint.h>

typedef unsigned short ushort_t;
typedef __attribute__((ext_vector_type(8)))  __bf16 bf16x8;
typedef __attribute__((ext_vector_type(16))) float  f32x16;

// ---------- helpers ----------

__device__ __forceinline__ unsigned int f2bf(float f) {
    unsigned int u = __float_as_uint(f);
    return (u + 0x7FFFu + ((u >> 16) & 1u)) >> 16;  // RNE
}

// Cayley sign for e_a * e_b in Cl(4,1), SIG = [1,1,1,1,-1]
__device__ __forceinline__ float cayley_sign(int a, int b) {
    int s = 0;
    int aa = a >> 1;
    while (aa) { s += __popc(aa & b); aa >>= 1; }
    float sign = (s & 1) ? -1.0f : 1.0f;
    if (a & b & 16) sign = -sign;   // only SIG[4] = -1
    return sign;
}

// async global->LDS, 16 bytes per lane. LDS dest is wave-uniform base + lane*16.
__device__ __forceinline__ void async16(const ushort_t* g, const ushort_t* l) {
    const __attribute__((address_space(1))) unsigned int* gp =
        (const __attribute__((address_space(1))) unsigned int*)(uintptr_t)g;
    __attribute__((address_space(3))) unsigned int* lp =
        (__attribute__((address_space(3))) unsigned int*)(unsigned int)(uintptr_t)l;
    __builtin_amdgcn_global_load_lds(gp, lp, 16, 0, 0);
}

// ---------- merged prep kernel (coalesced) ----------
// Swizzled operand chunk(blk, k_blk) = 4096 bf16: [kq(4)][row(128)][j(8)],
// i.e. element offset = kq*1024 + row*8 + j, with k = kq*8 + j.
// Thread t: row = (y&1)*64 + (t>>2), kq = t&3 -> reads 32 B contiguous f32,
// writes ONE uint4. Wave read footprint = 16 full 128-B lines per instruction.
__global__ __launch_bounds__(256) void prepAB(const float* __restrict__ x,
                                              const float* __restrict__ w,
                                              ushort_t* __restrict__ A_sw,
                                              ushort_t* __restrict__ B_sw) {
    const int k_blk = blockIdx.x;            // 0..127
    const int p_blk = blockIdx.y >> 1;       // 0..31 (128-row panel)
    const int sub   = blockIdx.y & 1;        // 0..1  (64-row half)
    const int t = threadIdx.x;               // 0..255
    const int r  = sub * 64 + (t >> 2);      // 0..127 row/col within panel
    const int kq = t & 3;                    // 0..3

    if (blockIdx.z == 0) {
        // ---- A: x viewed as 4096 x 4096 row-major f32 -> bf16 swizzled ----
        const float* src = x + (size_t)(p_blk * 128 + r) * 4096 + (size_t)k_blk * 32 + kq * 8;
        float4 a = ((const float4*)src)[0];
        float4 b = ((const float4*)src)[1];
        uint4 pk;
        pk.x = f2bf(a.x) | (f2bf(a.y) << 16);
        pk.y = f2bf(a.z) | (f2bf(a.w) << 16);
        pk.z = f2bf(b.x) | (f2bf(b.y) << 16);
        pk.w = f2bf(b.z) | (f2bf(b.w) << 16);
        ushort_t* chunk = A_sw + ((size_t)p_blk * 128 + k_blk) * 4096;
        *(uint4*)(chunk + kq * 1024 + r * 8) = pk;
    } else {
        // ---- B: Bt[n][f*32+i] = W[o, f, i^kc] * sgn(i, i^kc), n = o*32+kc ----
        const int n = p_blk * 128 + r;
        const int o = n >> 5;
        const int kc = n & 31;
        const float* wrow = w + (size_t)o * 4096 + (size_t)k_blk * 32;
        unsigned int pk[4];
#pragma unroll
        for (int pr = 0; pr < 4; ++pr) {
            const int i0 = kq * 8 + pr * 2, i1 = i0 + 1;
            const int j0 = i0 ^ kc, j1 = i1 ^ kc;
            float v0 = wrow[j0] * cayley_sign(i0, j0);
            float v1 = wrow[j1] * cayley_sign(i1, j1);
            pk[pr] = f2bf(v0) | (f2bf(v1) << 16);
        }
        uint4 u = {pk[0], pk[1], pk[2], pk[3]};
        ushort_t* chunk = B_sw + ((size_t)p_blk * 128 + k_blk) * 4096;
        *(uint4*)(chunk + kq * 1024 + r * 8) = u;
    }
}

// ---------- GEMM (32x32x16 bf16 MFMA) + fused multivector normalization ----------
// Single-barrier double-buffered K-loop: barrier -> prefetch(next) -> compute(cur).
__global__ __launch_bounds__(256) void gemm_norm(const ushort_t* __restrict__ A_sw,
                                                 const ushort_t* __restrict__ B_sw,
                                                 float* __restrict__ out) {
    __shared__ ushort_t As[2][4096];  // 2 x 8 KiB
    __shared__ ushort_t Bs[2][4096];  // 2 x 8 KiB

    const int n_blk = blockIdx.x;  // 0..31
    const int m_blk = blockIdx.y;  // 0..31
    const int t = threadIdx.x;
    const int wave = t >> 6;
    const int lane = t & 63;
    const int half = lane >> 5;    // 0..1 : k-subgroup
    const int l32  = lane & 31;    // m/n index within 32-tile
    const int wr = wave >> 1;      // wave row (0..1)
    const int wc = wave & 1;       // wave col (0..1)

    f32x16 acc[2][2];
#pragma unroll
    for (int a = 0; a < 2; ++a)
#pragma unroll
        for (int b = 0; b < 2; ++b)
#pragma unroll
            for (int i = 0; i < 16; ++i) acc[a][b][i] = 0.0f;

    const ushort_t* aPanel = A_sw + (size_t)m_blk * 128 * 4096;
    const ushort_t* bPanel = B_sw + (size_t)n_blk * 128 * 4096;

    // prologue: stage k-chunk 0 into buffer 0
    async16(aPanel + t * 8,        As[0] + wave * 512);
    async16(aPanel + 2048 + t * 8, As[0] + 2048 + wave * 512);
    async16(bPanel + t * 8,        Bs[0] + wave * 512);
    async16(bPanel + 2048 + t * 8, Bs[0] + 2048 + wave * 512);

    for (int kb = 0; kb < 128; ++kb) {
        const int cur = kb & 1;
        __syncthreads();   // buf[cur] staged; buf[cur^1] safe to overwrite

        if (kb + 1 < 128) {
            const ushort_t* gA = aPanel + (size_t)(kb + 1) * 4096;
            const ushort_t* gB = bPanel + (size_t)(kb + 1) * 4096;
            const int nxt = cur ^ 1;
            async16(gA + t * 8,        As[nxt] + wave * 512);
            async16(gA + 2048 + t * 8, As[nxt] + 2048 + wave * 512);
            async16(gB + t * 8,        Bs[nxt] + wave * 512);
            async16(gB + 2048 + t * 8, Bs[nxt] + 2048 + wave * 512);
        }

        // fragments: A[m=l32][k = half*8 + j] per k-half kh (k = kh*16 + half*8 + j)
        bf16x8 aF[2][2], bF[2][2];   // [tile][kh]
#pragma unroll
        for (int tm = 0; tm < 2; ++tm)
#pragma unroll
            for (int kh = 0; kh < 2; ++kh)
                aF[tm][kh] = *(const bf16x8*)&As[cur][(kh * 2 + half) * 1024 + (wr * 64 + tm * 32 + l32) * 8];
#pragma unroll
        for (int tn = 0; tn < 2; ++tn)
#pragma unroll
            for (int kh = 0; kh < 2; ++kh)
                bF[tn][kh] = *(const bf16x8*)&Bs[cur][(kh * 2 + half) * 1024 + (wc * 64 + tn * 32 + l32) * 8];

#pragma unroll
        for (int tm = 0; tm < 2; ++tm)
#pragma unroll
            for (int tn = 0; tn < 2; ++tn) {
                acc[tm][tn] = __builtin_amdgcn_mfma_f32_32x32x16_bf16(aF[tm][0], bF[tn][0], acc[tm][tn], 0, 0, 0);
                acc[tm][tn] = __builtin_amdgcn_mfma_f32_32x32x16_bf16(aF[tm][1], bF[tn][1], acc[tm][tn], 0, 0, 0);
            }
    }

    // Epilogue: fused normalization. 32x32 C/D layout (m74/m101):
    // col = lane&31, row = (reg&3) + 8*(reg>>2) + 4*(lane>>5).
    // Each 32-col tile spans exactly one output multivector group (n-group of 32).
    const int row0 = m_blk * 128 + wr * 64;
    const int col0 = n_blk * 128 + wc * 64;
#pragma unroll
    for (int tm = 0; tm < 2; ++tm) {
#pragma unroll
        for (int tn = 0; tn < 2; ++tn) {
            const int cbase = col0 + tn * 32 + l32;
#pragma unroll
            for (int reg = 0; reg < 16; ++reg) {
                float v = acc[tm][tn][reg];
                float p = v * v;
                p += __shfl_xor(p, 1);
                p += __shfl_xor(p, 2);
                p += __shfl_xor(p, 4);
                p += __shfl_xor(p, 8);
                p += __shfl_xor(p, 16);   // stays within the 32-lane half
                const float inv = rsqrtf(p + 1e-6f);
                const int row = row0 + tm * 32 + (reg & 3) + 8 * (reg >> 2) + 4 * half;
                out[(size_t)row * 4096 + cbase] = v * inv;
            }
        }
    }
}

// ---------- launch ----------

extern "C" void kernel_launch(void* const* d_in, const int* in_sizes, int n_in,
                              void* d_out, int out_size, void* d_ws, size_t ws_size,
                              hipStream_t stream) {
    const float* x = (const float*)d_in[0];     // 4096 x 128 x 32 f32
    const float* w = (const float*)d_in[1];     // 128 x 128 x 32 f32
    float* out = (float*)d_out;                 // 4096 x 128 x 32 f32

    ushort_t* A_sw = (ushort_t*)d_ws;                       // 32 MiB
    ushort_t* B_sw = A_sw + (size_t)4096 * 4096;            // 32 MiB

    prepAB<<<dim3(128, 64, 2), 256, 0, stream>>>(x, w, A_sw, B_sw);
    gemm_norm<<<dim3(32, 32), 256, 0, stream>>>(A_sw, B_sw, out);
}